// Round 3
// baseline (354.916 us; speedup 1.0000x reference)
//
#include <hip/hip_runtime.h>

// Problem constants (from reference)
#define NC 32768
#define ND 1024
#define NQ 256    // float4 chunks per row (ND/4)
#define NB 16384
#define KEEP 0.95f
#define OMK  0.05f   // 1 - keep
#define KCAP 16      // per-class sample-list cap; P(Poisson(0.5) >= 17) ~ 1e-19
#define RPB 8        // rows per block in loss kernel

typedef float f4 __attribute__((ext_vector_type(4)));

__device__ __forceinline__ f4 ntload(const f4* p) {
    return __builtin_nontemporal_load(p);
}
__device__ __forceinline__ void fma4(f4& a, float w, f4 b) {
    a.x = fmaf(w, b.x, a.x);
    a.y = fmaf(w, b.y, a.y);
    a.z = fmaf(w, b.z, a.z);
    a.w = fmaf(w, b.w, a.w);
}

// Kernel 1: count occurrences per class, scatter sample indices into
// per-class lists (order arbitrary; the index itself encodes batch order).
__global__ void count_scatter_kernel(const int* __restrict__ the_class,
                                     int* __restrict__ counts,
                                     int* __restrict__ idx_list) {
    int i = blockIdx.x * blockDim.x + threadIdx.x;
    if (i < NB) {
        int c = the_class[i];
        int pos = atomicAdd(&counts[c], 1);
        if (pos < KCAP) idx_list[c * KCAP + pos] = i;
    }
}

// Kernel 2: per-class EMA metadata. One thread per class:
// decay[c] = keep^cnt; elist[c][j] = {sample_idx, (1-keep)*keep^{#later occ}}
// Fully unrolled + predicated so idx[] stays in registers (no scratch).
__global__ void wprep_kernel(const int* __restrict__ counts,
                             const int* __restrict__ idx_list,
                             float* __restrict__ decays,
                             int2* __restrict__ elist) {
    int c = blockIdx.x * blockDim.x + threadIdx.x;
    int cnt = counts[c];
    // decay = keep^cnt via binary exponentiation
    float base = KEEP, r = 1.0f;
    for (int e = cnt; e > 0; e >>= 1) { if (e & 1) r *= base; base *= base; }
    decays[c] = r;
    int m = cnt < KCAP ? cnt : KCAP;
    int idx[KCAP];
    #pragma unroll
    for (int j = 0; j < KCAP; ++j)
        idx[j] = (j < m) ? idx_list[c * KCAP + j] : -1;  // sentinel never "later"
    #pragma unroll
    for (int j = 0; j < KCAP; ++j) {
        if (j < m) {
            int later = 0;
            #pragma unroll
            for (int l = 0; l < KCAP; ++l) later += (idx[l] > idx[j]);
            float w = OMK;
            for (int k = 0; k < later; ++k) w *= KEEP;
            int2 e; e.x = idx[j]; e.y = __float_as_int(w);
            elist[c * KCAP + j] = e;
        }
    }
}

// Kernel 3: fused EMA + L1 loss. Block = 256 threads handles RPB rows;
// thread q owns float4 column q of each row.
// Pipeline: ALL stream loads (s,t), ALL metadata (counts/decays/elist[0]),
// and the first-sample gather of every row are issued before any compute,
// so at most the rare (P~9%/row) j>=1 gathers expose latency.
__global__ __launch_bounds__(256) void loss_kernel(
    const float* __restrict__ s_logits,
    const float* __restrict__ t_logits,
    const float* __restrict__ logits,
    const int*   __restrict__ counts,
    const float* __restrict__ decays,
    const int2*  __restrict__ elist,
    float* __restrict__ out) {

    const int q  = threadIdx.x;        // 0..255 float4 column
    const int c0 = blockIdx.x * RPB;

    const f4* s4 = (const f4*)s_logits;
    const f4* t4 = (const f4*)t_logits;
    const f4* l4 = (const f4*)logits;

    // ---- issue the 16 independent stream loads first (max MLP) ----
    f4 sv[RPB], tv[RPB];
    #pragma unroll
    for (int r = 0; r < RPB; ++r) sv[r] = ntload(&s4[(size_t)(c0 + r) * NQ + q]);
    #pragma unroll
    for (int r = 0; r < RPB; ++r) tv[r] = ntload(&t4[(size_t)(c0 + r) * NQ + q]);

    // ---- per-row metadata (wave-uniform loads) ----
    float dec[RPB]; int m[RPB]; int2 e0[RPB];
    #pragma unroll
    for (int r = 0; r < RPB; ++r) {
        dec[r] = decays[c0 + r];
        int cnt = counts[c0 + r];
        m[r] = cnt < KCAP ? cnt : KCAP;
        e0[r] = elist[(c0 + r) * KCAP];    // garbage when m==0; never used then
    }

    // ---- first-sample gathers, issued up-front (predicated, wave-uniform) ----
    f4 lv0[RPB];
    #pragma unroll
    for (int r = 0; r < RPB; ++r) {
        if (m[r] > 0) lv0[r] = ntload(&l4[(size_t)e0[r].x * NQ + q]);
    }

    // ---- compute ----
    float lsum = 0.0f;
    #pragma unroll
    for (int r = 0; r < RPB; ++r) {
        const int c = c0 + r;
        f4 acc;
        acc.x = sv[r].x * dec[r];
        acc.y = sv[r].y * dec[r];
        acc.z = sv[r].z * dec[r];
        acc.w = sv[r].w * dec[r];
        if (m[r] > 0) {
            fma4(acc, __int_as_float(e0[r].y), lv0[r]);
            for (int j = 1; j < m[r]; ++j) {       // rare path: P(m>=2) ~ 9%
                int2 e = elist[c * KCAP + j];
                f4 lv = ntload(&l4[(size_t)e.x * NQ + q]);
                fma4(acc, __int_as_float(e.y), lv);
            }
        }
        lsum += fabsf(acc.x - tv[r].x) + fabsf(acc.y - tv[r].y) +
                fabsf(acc.z - tv[r].z) + fabsf(acc.w - tv[r].w);
    }

    // wave reduction (64 lanes) then cross-wave via LDS
    #pragma unroll
    for (int off = 32; off > 0; off >>= 1) lsum += __shfl_down(lsum, off);
    __shared__ float wsum[4];
    const int wave = threadIdx.x >> 6, lane = threadIdx.x & 63;
    if (lane == 0) wsum[wave] = lsum;
    __syncthreads();
    if (threadIdx.x == 0) {
        float total = (wsum[0] + wsum[1] + wsum[2] + wsum[3]) * (1.0f / NC);
        atomicAdd(out, total);
    }
}

extern "C" void kernel_launch(void* const* d_in, const int* in_sizes, int n_in,
                              void* d_out, int out_size, void* d_ws, size_t ws_size,
                              hipStream_t stream) {
    const float* s_logits  = (const float*)d_in[0];
    const float* t_logits  = (const float*)d_in[1];
    const float* logits    = (const float*)d_in[2];
    const int*   the_class = (const int*)d_in[3];
    float* out = (float*)d_out;

    // workspace layout (8B-aligned segments)
    int*   counts   = (int*)d_ws;                      // NC ints   (128 KB)
    int*   idx_list = counts + NC;                     // NC*KCAP   (2 MB)
    float* decays   = (float*)(idx_list + NC * KCAP);  // NC floats (128 KB)
    int2*  elist    = (int2*)(decays + NC);            // NC*KCAP int2 (4 MB)

    hipMemsetAsync(counts, 0, NC * sizeof(int), stream);
    hipMemsetAsync(d_out, 0, sizeof(float), stream);

    count_scatter_kernel<<<NB / 256, 256, 0, stream>>>(the_class, counts, idx_list);
    wprep_kernel<<<NC / 256, 256, 0, stream>>>(counts, idx_list, decays, elist);
    loss_kernel<<<NC / RPB, 256, 0, stream>>>(s_logits, t_logits, logits,
                                              counts, decays, elist, out);
}

// Round 4
// 345.357 us; speedup vs baseline: 1.0277x; 1.0277x over previous
//
#include <hip/hip_runtime.h>

// Problem constants (from reference)
#define NC 32768
#define ND 1024
#define NQ 256    // float4 chunks per row (ND/4)
#define NB 16384
#define KEEP 0.95f
#define OMK  0.05f   // 1 - keep
#define KCAP 16      // per-class sample-list cap; P(Poisson(0.5) >= 17) ~ 1e-19
#define RPB 4        // rows per block in loss kernel (4: keeps VGPR < 102 for 5 waves/SIMD)

typedef float f4 __attribute__((ext_vector_type(4)));

__device__ __forceinline__ void fma4(f4& a, float w, f4 b) {
    a.x = fmaf(w, b.x, a.x);
    a.y = fmaf(w, b.y, a.y);
    a.z = fmaf(w, b.z, a.z);
    a.w = fmaf(w, b.w, a.w);
}

// Kernel 1: count occurrences per class, scatter sample indices into
// per-class lists (order arbitrary; the index itself encodes batch order).
__global__ void count_scatter_kernel(const int* __restrict__ the_class,
                                     int* __restrict__ counts,
                                     int* __restrict__ idx_list) {
    int i = blockIdx.x * blockDim.x + threadIdx.x;
    if (i < NB) {
        int c = the_class[i];
        int pos = atomicAdd(&counts[c], 1);
        if (pos < KCAP) idx_list[c * KCAP + pos] = i;
    }
}

// Kernel 2: per-class EMA metadata. One thread per class:
// decay[c] = keep^cnt; elist[c][j] = {sample_idx, (1-keep)*keep^{#later occ}}
// Fully unrolled + predicated so idx[] stays in registers (no scratch).
__global__ void wprep_kernel(const int* __restrict__ counts,
                             const int* __restrict__ idx_list,
                             float* __restrict__ decays,
                             int2* __restrict__ elist) {
    int c = blockIdx.x * blockDim.x + threadIdx.x;
    int cnt = counts[c];
    // decay = keep^cnt via binary exponentiation
    float base = KEEP, r = 1.0f;
    for (int e = cnt; e > 0; e >>= 1) { if (e & 1) r *= base; base *= base; }
    decays[c] = r;
    int m = cnt < KCAP ? cnt : KCAP;
    int idx[KCAP];
    #pragma unroll
    for (int j = 0; j < KCAP; ++j)
        idx[j] = (j < m) ? idx_list[c * KCAP + j] : -1;  // sentinel never "later"
    #pragma unroll
    for (int j = 0; j < KCAP; ++j) {
        if (j < m) {
            int later = 0;
            #pragma unroll
            for (int l = 0; l < KCAP; ++l) later += (idx[l] > idx[j]);
            float w = OMK;
            for (int k = 0; k < later; ++k) w *= KEEP;
            int2 e; e.x = idx[j]; e.y = __float_as_int(w);
            elist[c * KCAP + j] = e;
        }
    }
}

// Kernel 3: fused EMA + L1 loss. Block = 256 threads handles RPB rows;
// thread q owns float4 column q of each row.
// Pipeline: ALL stream loads (s,t), ALL metadata (counts/decays/elist[0]),
// and the first-sample gather of every row are issued before any compute.
// RPB=4 + launch_bounds(256,5) keeps VGPR <= 102 -> 5 waves/SIMD resident
// (round-3 lesson: RPB=8 preload hit 132 VGPR -> 3 waves/SIMD -> regression).
__global__ __launch_bounds__(256, 5) void loss_kernel(
    const float* __restrict__ s_logits,
    const float* __restrict__ t_logits,
    const float* __restrict__ logits,
    const int*   __restrict__ counts,
    const float* __restrict__ decays,
    const int2*  __restrict__ elist,
    float* __restrict__ out) {

    const int q  = threadIdx.x;        // 0..255 float4 column
    const int c0 = blockIdx.x * RPB;

    const f4* s4 = (const f4*)s_logits;
    const f4* t4 = (const f4*)t_logits;
    const f4* l4 = (const f4*)logits;

    // ---- issue the 8 independent stream loads first (MLP) ----
    f4 sv[RPB], tv[RPB];
    #pragma unroll
    for (int r = 0; r < RPB; ++r) sv[r] = s4[(size_t)(c0 + r) * NQ + q];
    #pragma unroll
    for (int r = 0; r < RPB; ++r) tv[r] = t4[(size_t)(c0 + r) * NQ + q];

    // ---- per-row metadata (wave-uniform loads) ----
    float dec[RPB]; int m[RPB]; int2 e0[RPB];
    #pragma unroll
    for (int r = 0; r < RPB; ++r) {
        dec[r] = decays[c0 + r];
        int cnt = counts[c0 + r];
        m[r] = cnt < KCAP ? cnt : KCAP;
        e0[r] = elist[(c0 + r) * KCAP];    // garbage when m==0; never used then
    }

    // ---- first-sample gathers, issued up-front (predicated, wave-uniform) ----
    f4 lv0[RPB];
    #pragma unroll
    for (int r = 0; r < RPB; ++r) {
        if (m[r] > 0) lv0[r] = l4[(size_t)e0[r].x * NQ + q];
    }

    // ---- compute ----
    float lsum = 0.0f;
    #pragma unroll
    for (int r = 0; r < RPB; ++r) {
        const int c = c0 + r;
        f4 acc;
        acc.x = sv[r].x * dec[r];
        acc.y = sv[r].y * dec[r];
        acc.z = sv[r].z * dec[r];
        acc.w = sv[r].w * dec[r];
        if (m[r] > 0) {
            fma4(acc, __int_as_float(e0[r].y), lv0[r]);
            for (int j = 1; j < m[r]; ++j) {       // rare path: P(m>=2) ~ 9%
                int2 e = elist[c * KCAP + j];
                f4 lv = l4[(size_t)e.x * NQ + q];
                fma4(acc, __int_as_float(e.y), lv);
            }
        }
        lsum += fabsf(acc.x - tv[r].x) + fabsf(acc.y - tv[r].y) +
                fabsf(acc.z - tv[r].z) + fabsf(acc.w - tv[r].w);
    }

    // wave reduction (64 lanes) then cross-wave via LDS
    #pragma unroll
    for (int off = 32; off > 0; off >>= 1) lsum += __shfl_down(lsum, off);
    __shared__ float wsum[4];
    const int wave = threadIdx.x >> 6, lane = threadIdx.x & 63;
    if (lane == 0) wsum[wave] = lsum;
    __syncthreads();
    if (threadIdx.x == 0) {
        float total = (wsum[0] + wsum[1] + wsum[2] + wsum[3]) * (1.0f / NC);
        atomicAdd(out, total);
    }
}

extern "C" void kernel_launch(void* const* d_in, const int* in_sizes, int n_in,
                              void* d_out, int out_size, void* d_ws, size_t ws_size,
                              hipStream_t stream) {
    const float* s_logits  = (const float*)d_in[0];
    const float* t_logits  = (const float*)d_in[1];
    const float* logits    = (const float*)d_in[2];
    const int*   the_class = (const int*)d_in[3];
    float* out = (float*)d_out;

    // workspace layout (8B-aligned segments)
    int*   counts   = (int*)d_ws;                      // NC ints   (128 KB)
    int*   idx_list = counts + NC;                     // NC*KCAP   (2 MB)
    float* decays   = (float*)(idx_list + NC * KCAP);  // NC floats (128 KB)
    int2*  elist    = (int2*)(decays + NC);            // NC*KCAP int2 (4 MB)

    hipMemsetAsync(counts, 0, NC * sizeof(int), stream);
    hipMemsetAsync(d_out, 0, sizeof(float), stream);

    count_scatter_kernel<<<NB / 256, 256, 0, stream>>>(the_class, counts, idx_list);
    wprep_kernel<<<NC / 256, 256, 0, stream>>>(counts, idx_list, decays, elist);
    loss_kernel<<<NC / RPB, 256, 0, stream>>>(s_logits, t_logits, logits,
                                              counts, decays, elist, out);
}